// Round 5
// baseline (148.258 us; speedup 1.0000x reference)
//
#include <hip/hip_runtime.h>
#include <hip/hip_bf16.h>

#define NB 32        // batch (docs)
#define NT 4096      // tokens per doc
#define NH 256       // hidden
#define NS 256       // MAX_SENTS
#define REP 8        // DIAGNOSTIC: re-read x REP times (divide by REP*n). Set to 1 after.

// ---------------------------------------------------------------------------
// Fused kernel (R3 structure + unroll-4 + REP diagnostic loop).
// Grid (NS/4, NB), 256 threads (4 waves). Phase 1: block-redundant boundary
// scan (int4 loads + shfl_up wave scan + 2-barrier cross-wave fixup) -> LDS
// bpos/len. Phase 2: one sentence per wave, float4 lane loads, 4 accumulators,
// REP passes over the sentence rows, store float4 mean/REP.
// ---------------------------------------------------------------------------
__global__ void hie_fused_kernel(const float* __restrict__ x,
                                 const int* __restrict__ batch_x,
                                 float* __restrict__ out) {
    const int b    = blockIdx.y;
    const int tid  = threadIdx.x;
    const int wid  = tid >> 6;
    const int lane = tid & 63;

    __shared__ int sm_w[5];
    __shared__ int sm_bpos[NS + 1];
    __shared__ int sm_len;

    // ---- phase 1: boundary scan ----
    const int  base = tid * 16;
    const int4* rp  = reinterpret_cast<const int4*>(batch_x + (size_t)b * NT + base);
    int flags = 0, cnt = 0;
#pragma unroll
    for (int i = 0; i < 4; ++i) {
        int4 v = rp[i];
        int f0 = (v.x == 1), f1 = (v.y == 1), f2 = (v.z == 1), f3 = (v.w == 1);
        flags |= (f0 << (4 * i)) | (f1 << (4 * i + 1)) | (f2 << (4 * i + 2)) | (f3 << (4 * i + 3));
        cnt   += f0 + f1 + f2 + f3;
    }

    int inc = cnt;
#pragma unroll
    for (int off = 1; off < 64; off <<= 1) {
        int u = __shfl_up(inc, off, 64);
        if (lane >= off) inc += u;
    }
    if (lane == 63) sm_w[wid] = inc;
    __syncthreads();
    if (tid == 0) {
        int run = 0;
#pragma unroll
        for (int w = 0; w < 4; ++w) { int t = sm_w[w]; sm_w[w] = run; run += t; }
        sm_w[4]    = run;
        sm_len     = run > NS ? NS : run;
        sm_bpos[0] = -1;
    }
    __syncthreads();

    int idx = (inc - cnt) + sm_w[wid];
#pragma unroll
    for (int i = 0; i < 16; ++i) {
        if ((flags >> i) & 1) {
            if (idx < NS) sm_bpos[idx + 1] = base + i;
            ++idx;
        }
    }
    __syncthreads();

    if (blockIdx.x == 0 && tid == 0)
        out[(size_t)NB * NS * NH + b] = (float)sm_w[4];

    // ---- phase 2: one sentence per wave ----
    const int s = blockIdx.x * 4 + wid;
    float* o = out + ((size_t)b * NS + s) * NH + lane * 4;

    if (s >= sm_len) {
        *reinterpret_cast<float4*>(o) = make_float4(0.f, 0.f, 0.f, 0.f);
        return;
    }

    const int end   = sm_bpos[s + 1];
    const int start = sm_bpos[s] + 1;
    const int n     = end - start + 1;

    const float4* pbase = reinterpret_cast<const float4*>(
                              x + ((size_t)b * NT + start) * NH) + lane;
    float4 a0 = make_float4(0.f, 0.f, 0.f, 0.f);
    float4 a1 = make_float4(0.f, 0.f, 0.f, 0.f);
    float4 a2 = make_float4(0.f, 0.f, 0.f, 0.f);
    float4 a3 = make_float4(0.f, 0.f, 0.f, 0.f);

    for (int r = 0; r < REP; ++r) {
        const float4* p = pbase;
        int k = 0;
        for (; k + 4 <= n; k += 4) {
            float4 v0 = p[0 * (NH / 4)];
            float4 v1 = p[1 * (NH / 4)];
            float4 v2 = p[2 * (NH / 4)];
            float4 v3 = p[3 * (NH / 4)];
            a0.x += v0.x; a0.y += v0.y; a0.z += v0.z; a0.w += v0.w;
            a1.x += v1.x; a1.y += v1.y; a1.z += v1.z; a1.w += v1.w;
            a2.x += v2.x; a2.y += v2.y; a2.z += v2.z; a2.w += v2.w;
            a3.x += v3.x; a3.y += v3.y; a3.z += v3.z; a3.w += v3.w;
            p += 4 * (NH / 4);
        }
        for (; k < n; ++k) {
            float4 v0 = p[0];
            a0.x += v0.x; a0.y += v0.y; a0.z += v0.z; a0.w += v0.w;
            p += NH / 4;
        }
    }

    const float inv = 1.0f / (float)(REP * n);
    *reinterpret_cast<float4*>(o) =
        make_float4((a0.x + a1.x + a2.x + a3.x) * inv,
                    (a0.y + a1.y + a2.y + a3.y) * inv,
                    (a0.z + a1.z + a2.z + a3.z) * inv,
                    (a0.w + a1.w + a2.w + a3.w) * inv);
}

extern "C" void kernel_launch(void* const* d_in, const int* in_sizes, int n_in,
                              void* d_out, int out_size, void* d_ws, size_t ws_size,
                              hipStream_t stream) {
    const float* hie_ins = (const float*)d_in[0];
    const int*   batch_x = (const int*)d_in[1];
    float*       out     = (float*)d_out;

    hie_fused_kernel<<<dim3(NS / 4, NB), dim3(256), 0, stream>>>(hie_ins, batch_x, out);
}

// Round 6
// 27.810 us; speedup vs baseline: 5.3310x; 5.3310x over previous
//
#include <hip/hip_runtime.h>
#include <hip/hip_bf16.h>

#define NB 32        // batch (docs)
#define NT 4096      // tokens per doc
#define NH 256       // hidden
#define NS 256       // MAX_SENTS

// ---------------------------------------------------------------------------
// Fused kernel, load-balanced grid.
// Grid (x=NB docs, y=NS/4 sentence-groups) so linear block id = b + 32*g:
// the stride-256 round-robin of resident blocks onto CUs gives each CU one
// doc x 8 spread groups ~= 512 KiB regardless of doc (per-doc valid bytes are
// ~constant). The old (x=groups, y=docs) layout pinned each CU to one group
// index -> 3x per-CU byte imbalance (g<23 CUs ~960 KiB, g>=51 CUs mostly
// zero-fill).
// Phase 1: block-redundant boundary scan (int4 + shfl_up + 2-barrier fixup).
// Phase 2: one sentence per wave, float4 lane loads, unroll-4.
// ---------------------------------------------------------------------------
__global__ void hie_fused_kernel(const float* __restrict__ x,
                                 const int* __restrict__ batch_x,
                                 float* __restrict__ out) {
    const int b    = blockIdx.x;               // doc
    const int g    = blockIdx.y;               // sentence group
    const int tid  = threadIdx.x;
    const int wid  = tid >> 6;
    const int lane = tid & 63;

    __shared__ int sm_w[5];
    __shared__ int sm_bpos[NS + 1];
    __shared__ int sm_len;

    // ---- phase 1: boundary scan ----
    const int  base = tid * 16;
    const int4* rp  = reinterpret_cast<const int4*>(batch_x + (size_t)b * NT + base);
    int flags = 0, cnt = 0;
#pragma unroll
    for (int i = 0; i < 4; ++i) {
        int4 v = rp[i];
        int f0 = (v.x == 1), f1 = (v.y == 1), f2 = (v.z == 1), f3 = (v.w == 1);
        flags |= (f0 << (4 * i)) | (f1 << (4 * i + 1)) | (f2 << (4 * i + 2)) | (f3 << (4 * i + 3));
        cnt   += f0 + f1 + f2 + f3;
    }

    int inc = cnt;
#pragma unroll
    for (int off = 1; off < 64; off <<= 1) {
        int u = __shfl_up(inc, off, 64);
        if (lane >= off) inc += u;
    }
    if (lane == 63) sm_w[wid] = inc;
    __syncthreads();
    if (tid == 0) {
        int run = 0;
#pragma unroll
        for (int w = 0; w < 4; ++w) { int t = sm_w[w]; sm_w[w] = run; run += t; }
        sm_w[4]    = run;
        sm_len     = run > NS ? NS : run;
        sm_bpos[0] = -1;
    }
    __syncthreads();

    int idx = (inc - cnt) + sm_w[wid];
#pragma unroll
    for (int i = 0; i < 16; ++i) {
        if ((flags >> i) & 1) {
            if (idx < NS) sm_bpos[idx + 1] = base + i;
            ++idx;
        }
    }
    __syncthreads();

    if (g == 0 && tid == 0)
        out[(size_t)NB * NS * NH + b] = (float)sm_w[4];   // doc_lens tail

    // ---- phase 2: one sentence per wave ----
    const int s = g * 4 + wid;
    float* o = out + ((size_t)b * NS + s) * NH + lane * 4;

    if (s >= sm_len) {
        *reinterpret_cast<float4*>(o) = make_float4(0.f, 0.f, 0.f, 0.f);
        return;
    }

    const int end   = sm_bpos[s + 1];
    const int start = sm_bpos[s] + 1;
    const int n     = end - start + 1;

    const float4* p = reinterpret_cast<const float4*>(
                          x + ((size_t)b * NT + start) * NH) + lane;
    float4 a0 = make_float4(0.f, 0.f, 0.f, 0.f);
    float4 a1 = make_float4(0.f, 0.f, 0.f, 0.f);
    float4 a2 = make_float4(0.f, 0.f, 0.f, 0.f);
    float4 a3 = make_float4(0.f, 0.f, 0.f, 0.f);

    int k = 0;
    for (; k + 4 <= n; k += 4) {
        float4 v0 = p[0 * (NH / 4)];
        float4 v1 = p[1 * (NH / 4)];
        float4 v2 = p[2 * (NH / 4)];
        float4 v3 = p[3 * (NH / 4)];
        a0.x += v0.x; a0.y += v0.y; a0.z += v0.z; a0.w += v0.w;
        a1.x += v1.x; a1.y += v1.y; a1.z += v1.z; a1.w += v1.w;
        a2.x += v2.x; a2.y += v2.y; a2.z += v2.z; a2.w += v2.w;
        a3.x += v3.x; a3.y += v3.y; a3.z += v3.z; a3.w += v3.w;
        p += 4 * (NH / 4);
    }
    for (; k < n; ++k) {
        float4 v0 = p[0];
        a0.x += v0.x; a0.y += v0.y; a0.z += v0.z; a0.w += v0.w;
        p += NH / 4;
    }

    const float inv = 1.0f / (float)n;
    *reinterpret_cast<float4*>(o) =
        make_float4((a0.x + a1.x + a2.x + a3.x) * inv,
                    (a0.y + a1.y + a2.y + a3.y) * inv,
                    (a0.z + a1.z + a2.z + a3.z) * inv,
                    (a0.w + a1.w + a2.w + a3.w) * inv);
}

extern "C" void kernel_launch(void* const* d_in, const int* in_sizes, int n_in,
                              void* d_out, int out_size, void* d_ws, size_t ws_size,
                              hipStream_t stream) {
    const float* hie_ins = (const float*)d_in[0];
    const int*   batch_x = (const int*)d_in[1];
    float*       out     = (float*)d_out;

    hie_fused_kernel<<<dim3(NB, NS / 4), dim3(256), 0, stream>>>(hie_ins, batch_x, out);
}

// Round 7
// 27.420 us; speedup vs baseline: 5.4070x; 1.0143x over previous
//
#include <hip/hip_runtime.h>
#include <hip/hip_bf16.h>

#define NB 32        // batch (docs)
#define NT 4096      // tokens per doc
#define NH 256       // hidden
#define NS 256       // MAX_SENTS

// ---------------------------------------------------------------------------
// Fused kernel, load-balanced grid, fine-grained sentence striping.
// Grid (x=NB docs, y=NS/4). Block (b,g), wave w handles sentence s = w*64+g.
// Per-CU resident set = one doc x sentences s ≡ g0 (mod 8): valid-sentence
// count per CU varies by <=1 (the old s=4g+w mapping quantized per-CU work in
// units of 4 sentences -> ±20% byte imbalance; this is ±4%).
// Phase 1: block-redundant boundary scan (int4 + shfl_up + 2-barrier fixup).
// Phase 2: one sentence per wave, float4 lane loads, unroll-4.
// Invalid sentences zero-fill (poisoned d_out fully rewritten every call).
// ---------------------------------------------------------------------------
__global__ void hie_fused_kernel(const float* __restrict__ x,
                                 const int* __restrict__ batch_x,
                                 float* __restrict__ out) {
    const int b    = blockIdx.x;               // doc
    const int g    = blockIdx.y;               // stripe index 0..63
    const int tid  = threadIdx.x;
    const int wid  = tid >> 6;
    const int lane = tid & 63;

    __shared__ int sm_w[5];
    __shared__ int sm_bpos[NS + 1];
    __shared__ int sm_len;

    // ---- phase 1: boundary scan ----
    const int  base = tid * 16;
    const int4* rp  = reinterpret_cast<const int4*>(batch_x + (size_t)b * NT + base);
    int flags = 0, cnt = 0;
#pragma unroll
    for (int i = 0; i < 4; ++i) {
        int4 v = rp[i];
        int f0 = (v.x == 1), f1 = (v.y == 1), f2 = (v.z == 1), f3 = (v.w == 1);
        flags |= (f0 << (4 * i)) | (f1 << (4 * i + 1)) | (f2 << (4 * i + 2)) | (f3 << (4 * i + 3));
        cnt   += f0 + f1 + f2 + f3;
    }

    int inc = cnt;
#pragma unroll
    for (int off = 1; off < 64; off <<= 1) {
        int u = __shfl_up(inc, off, 64);
        if (lane >= off) inc += u;
    }
    if (lane == 63) sm_w[wid] = inc;
    __syncthreads();
    if (tid == 0) {
        int run = 0;
#pragma unroll
        for (int w = 0; w < 4; ++w) { int t = sm_w[w]; sm_w[w] = run; run += t; }
        sm_w[4]    = run;
        sm_len     = run > NS ? NS : run;
        sm_bpos[0] = -1;
    }
    __syncthreads();

    int idx = (inc - cnt) + sm_w[wid];
#pragma unroll
    for (int i = 0; i < 16; ++i) {
        if ((flags >> i) & 1) {
            if (idx < NS) sm_bpos[idx + 1] = base + i;
            ++idx;
        }
    }
    __syncthreads();

    if (g == 0 && tid == 0)
        out[(size_t)NB * NS * NH + b] = (float)sm_w[4];   // doc_lens tail

    // ---- phase 2: one sentence per wave (striped: s = w*64 + g) ----
    const int s = wid * 64 + g;
    float* o = out + ((size_t)b * NS + s) * NH + lane * 4;

    if (s >= sm_len) {
        *reinterpret_cast<float4*>(o) = make_float4(0.f, 0.f, 0.f, 0.f);
        return;
    }

    const int end   = sm_bpos[s + 1];
    const int start = sm_bpos[s] + 1;
    const int n     = end - start + 1;

    const float4* p = reinterpret_cast<const float4*>(
                          x + ((size_t)b * NT + start) * NH) + lane;
    float4 a0 = make_float4(0.f, 0.f, 0.f, 0.f);
    float4 a1 = make_float4(0.f, 0.f, 0.f, 0.f);
    float4 a2 = make_float4(0.f, 0.f, 0.f, 0.f);
    float4 a3 = make_float4(0.f, 0.f, 0.f, 0.f);

    int k = 0;
    for (; k + 4 <= n; k += 4) {
        float4 v0 = p[0 * (NH / 4)];
        float4 v1 = p[1 * (NH / 4)];
        float4 v2 = p[2 * (NH / 4)];
        float4 v3 = p[3 * (NH / 4)];
        a0.x += v0.x; a0.y += v0.y; a0.z += v0.z; a0.w += v0.w;
        a1.x += v1.x; a1.y += v1.y; a1.z += v1.z; a1.w += v1.w;
        a2.x += v2.x; a2.y += v2.y; a2.z += v2.z; a2.w += v2.w;
        a3.x += v3.x; a3.y += v3.y; a3.z += v3.z; a3.w += v3.w;
        p += 4 * (NH / 4);
    }
    for (; k < n; ++k) {
        float4 v0 = p[0];
        a0.x += v0.x; a0.y += v0.y; a0.z += v0.z; a0.w += v0.w;
        p += NH / 4;
    }

    const float inv = 1.0f / (float)n;
    *reinterpret_cast<float4*>(o) =
        make_float4((a0.x + a1.x + a2.x + a3.x) * inv,
                    (a0.y + a1.y + a2.y + a3.y) * inv,
                    (a0.z + a1.z + a2.z + a3.z) * inv,
                    (a0.w + a1.w + a2.w + a3.w) * inv);
}

extern "C" void kernel_launch(void* const* d_in, const int* in_sizes, int n_in,
                              void* d_out, int out_size, void* d_ws, size_t ws_size,
                              hipStream_t stream) {
    const float* hie_ins = (const float*)d_in[0];
    const int*   batch_x = (const int*)d_in[1];
    float*       out     = (float*)d_out;

    hie_fused_kernel<<<dim3(NB, NS / 4), dim3(256), 0, stream>>>(hie_ins, batch_x, out);
}